// Round 9
// baseline (86.718 us; speedup 1.0000x reference)
//
#include <hip/hip_runtime.h>
#include <math.h>

#define BB 4
#define NN 6
#define DD 41
#define CC 64
#define FHh 16
#define FWw 44
#define NXg 200
#define NYg 200
#define NZg 1
#define NSLOT 128
#define NOVF  (FHh*DD)                 // 656 worst-case points per column
#define XYg (NXg*NYg)                  // 40000
#define NVOX (BB*NZg*NXg*NYg)          // 160000
#define NCOL (BB*NN*FWw)               // 1056 columns
#define NPIX (BB*NN*FHh*FWw)           // 16896
#define MAXREC (NCOL*NOVF)             // 692736 absolute worst case
#define RECI 20                        // ints per record (80 B): vox,next,col,pad,coef[16]

// ws byte offsets
#define HEAD_OFF 0
#define CNT_OFF  (NVOX*4)                       // 640000
#define REC_OFF  (1u<<20)                       // 1 MiB
#define FT_OFF   (REC_OFF + MAXREC*RECI*4)      // 56,467,456 (16B aligned)
#define WS_NEED  (FT_OFF + NCOL*FHh*CC*4)       // ~60.8 MB

__device__ __forceinline__ void inv3x3d(const double m[9], double o[9]) {
    double a=m[0],b=m[1],c=m[2],d=m[3],e=m[4],f=m[5],g=m[6],h=m[7],i=m[8];
    double A = e*i - f*h;
    double Bv = -(d*i - f*g);
    double Cv = d*h - e*g;
    double det = a*A + b*Bv + c*Cv;
    double r = 1.0/det;
    o[0]=A*r;  o[1]=-(b*i-c*h)*r; o[2]=(b*f-c*e)*r;
    o[3]=Bv*r; o[4]=(a*i-c*g)*r;  o[5]=-(a*f-c*d)*r;
    o[6]=Cv*r; o[7]=-(a*h-b*g)*r; o[8]=(a*e-b*d)*r;
}

// -------- build: per-column dedup -> records + head linked list + fT --------
__global__ __launch_bounds__(256)
void lss_build(const float* __restrict__ xf,
               const float* __restrict__ rots,
               const float* __restrict__ trans,
               const float* __restrict__ intr,
               const float* __restrict__ prots,
               const float* __restrict__ ptrans,
               int* __restrict__ head,
               int* __restrict__ cnt,
               int* __restrict__ recs,
               float* __restrict__ fT)
{
    __shared__ float s_lg[FHh * FWw];
    __shared__ float s_feat[FHh * CC];
    __shared__ float s_coef[NSLOT * 17];
    __shared__ int   s_keys[NSLOT];
    __shared__ short s_list[NSLOT];
    __shared__ int   s_nslot;
    __shared__ int2  s_ovf[NOVF];
    __shared__ float s_ovfw[NOVF];
    __shared__ int   s_ovfcnt;
    __shared__ int   s_base;

    const int tid  = threadIdx.x;
    const int lane = tid & 63;
    const int wv   = tid >> 6;          // 0..3

    // XCD swizzle: 1056 = 8*132
    const int obid = blockIdx.x;
    const int bid  = (obid & 7) * (NCOL / 8) + (obid >> 3);
    const int w   = bid % FWw;
    const int rem = bid / FWw;
    const int n   = rem % NN;
    const int b   = rem / NN;
    const int cam = b*NN + n;
    const float* colbase = xf + (size_t)cam * (DD+CC) * FHh * FWw + w;

    if (tid < NSLOT) s_keys[tid] = -1;
    for (int i = tid; i < NSLOT*17; i += 256) s_coef[i] = 0.0f;
    if (tid == 0) { s_nslot = 0; s_ovfcnt = 0; }

    // stage the whole column (1680 scalars)
    for (int t = tid; t < (DD+CC)*FHh; t += 256) {
        int h  = t / (DD+CC);
        int ch = t - h*(DD+CC);
        float v = colbase[(size_t)ch * (FHh*FWw) + h * FWw];
        if (ch < DD) s_lg[h*FWw + ch] = v;
        else         s_feat[(h << 6) + (ch - DD)] = v;
    }

    // per-camera transform (f64, redundant per thread)
    double K9[9], P9[9], R9[9];
    #pragma unroll
    for (int i = 0; i < 9; ++i) {
        K9[i] = (double)intr [cam*9 + i];
        P9[i] = (double)prots[cam*9 + i];
        R9[i] = (double)rots [cam*9 + i];
    }
    double Kinv[9], Pinv[9];
    inv3x3d(K9, Kinv);
    inv3x3d(P9, Pinv);
    double M[9];
    #pragma unroll
    for (int i = 0; i < 3; ++i)
        #pragma unroll
        for (int j = 0; j < 3; ++j)
            M[i*3+j] = R9[i*3+0]*Kinv[0*3+j] + R9[i*3+1]*Kinv[1*3+j] + R9[i*3+2]*Kinv[2*3+j];
    const double tx  = (double)trans [cam*3+0], ty  = (double)trans [cam*3+1], tz  = (double)trans [cam*3+2];
    const double ptx = (double)ptrans[cam*3+0], pty = (double)ptrans[cam*3+1], ptz = (double)ptrans[cam*3+2];

    __syncthreads();

    // softmax + geometry + hash insert; wave wv handles h = 4wv..4wv+3
    int      last_vox  = -1;
    unsigned last_slot = 0;
    for (int r = 0; r < 4; ++r) {
        const int h = (wv << 2) + r;
        float logit = (lane < DD) ? s_lg[h*FWw + lane] : -INFINITY;
        float mx = logit;
        #pragma unroll
        for (int off = 32; off; off >>= 1) mx = fmaxf(mx, __shfl_xor(mx, off));
        float ex = (lane < DD) ? expf(logit - mx) : 0.0f;
        float sm = ex;
        #pragma unroll
        for (int off = 32; off; off >>= 1) sm += __shfl_xor(sm, off);
        const float wgt = ex / sm;

        int vox = -1;
        if (lane < DD) {
            double dz = 4.0 + (double)lane;
            double xs = (double)w * (703.0/43.0);
            double ys = (double)h * 17.0;
            double px = xs - ptx, py = ys - pty, pz = dz - ptz;
            double qx = Pinv[0]*px + Pinv[1]*py + Pinv[2]*pz;
            double qy = Pinv[3]*px + Pinv[4]*py + Pinv[5]*pz;
            double qz = Pinv[6]*px + Pinv[7]*py + Pinv[8]*pz;
            qx *= qz; qy *= qz;
            double gx = M[0]*qx + M[1]*qy + M[2]*qz + tx;
            double gy = M[3]*qx + M[4]*qy + M[5]*qz + ty;
            double gz = M[6]*qx + M[7]*qy + M[8]*qz + tz;
            double fx = floor((gx + 50.0) / 0.5);
            double fy = floor((gy + 50.0) / 0.5);
            double fz = floor((gz + 10.0) / 20.0);
            if (fx >= 0.0 && fx < (double)NXg &&
                fy >= 0.0 && fy < (double)NYg &&
                fz >= 0.0 && fz < (double)NZg) {
                int ix = (int)fx, iy = (int)fy, iz = (int)fz;
                vox = ((b*NZg + iz)*NXg + ix)*NYg + iy;   // < NVOX
            }
        }

        if (vox >= 0) {
            if (vox == last_vox) {
                atomicAdd(&s_coef[last_slot*17 + h], wgt);
            } else {
                unsigned slot = (((unsigned)vox * 2654435761u) >> 18) & (NSLOT-1);
                bool done = false;
                for (int probe = 0; probe < NSLOT; ++probe) {
                    int prev = atomicCAS(&s_keys[slot], -1, vox);
                    if (prev == -1) {
                        int k = atomicAdd(&s_nslot, 1);
                        s_list[k] = (short)slot;
                    }
                    if (prev == -1 || prev == vox) {
                        atomicAdd(&s_coef[slot*17 + h], wgt);
                        last_vox = vox; last_slot = slot;
                        done = true;
                        break;
                    }
                    slot = (slot + 1) & (NSLOT-1);
                }
                if (!done) {
                    int k = atomicAdd(&s_ovfcnt, 1);
                    s_ovf[k]  = make_int2(vox, h);
                    s_ovfw[k] = wgt;
                    last_vox = -1;
                }
            }
        }
    }

    __syncthreads();

    const int nocc = s_nslot;
    const int novf = s_ovfcnt;
    if (tid == 0) s_base = atomicAdd(cnt, nocc + novf);
    // publish features for this column: fT[bid][h][c]
    {
        float* ft = fT + (size_t)bid * (FHh*CC);
        for (int i = tid; i < FHh*CC; i += 256) ft[i] = s_feat[i];
    }
    __syncthreads();
    const int base = s_base;

    // one record per occupied slot
    for (int e = wv; e < nocc; e += 4) {
        int slot = s_list[e];
        int vox  = s_keys[slot];
        int ridx = base + e;
        int* rec = recs + (size_t)ridx * RECI;
        if (lane >= 32 && lane < 48)
            ((float*)rec)[4 + (lane-32)] = s_coef[slot*17 + (lane-32)];
        if (lane == 0) {
            rec[0] = vox;
            rec[2] = bid;
            rec[1] = atomicExch(&head[vox], ridx);   // device-scope publish
        }
    }
    // overflow records (rare, generic fallback)
    for (int e = wv; e < novf; e += 4) {
        int vox = s_ovf[e].x, h = s_ovf[e].y;
        int ridx = base + nocc + e;
        int* rec = recs + (size_t)ridx * RECI;
        if (lane >= 32 && lane < 48)
            ((float*)rec)[4 + (lane-32)] = ((lane-32) == h) ? s_ovfw[e] : 0.0f;
        if (lane == 0) {
            rec[0] = vox;
            rec[2] = bid;
            rec[1] = atomicExch(&head[vox], ridx);
        }
    }
}

// -------- gather: walk per-voxel record chains, write final layout ----------
// block = 64-xy tile of one bz; wave wv owns cells wv,wv+4,... ; lane = channel
__global__ __launch_bounds__(256)
void lss_gather(const int* __restrict__ head,
                const int* __restrict__ recs,
                const float* __restrict__ fT,
                float* __restrict__ out)
{
    __shared__ float s_acc[CC * 65];         // [c][cell], pad 65
    const int blk  = blockIdx.x;             // BB*NZg*625
    const int bz   = blk / 625;
    const int xy0  = (blk % 625) * 64;
    const int tid  = threadIdx.x;
    const int lane = tid & 63;
    const int wv   = tid >> 6;               // 0..3

    for (int cell = wv; cell < 64; cell += 4) {
        const int vox = bz * XYg + xy0 + cell;
        float a = 0.0f;
        int ptr = head[vox];
        while (ptr >= 0) {
            const int* rec = recs + (size_t)ptr * RECI;
            const int col  = rec[2];
            const float4* cp = (const float4*)(rec + 4);
            float4 c0 = cp[0], c1 = cp[1], c2 = cp[2], c3 = cp[3];
            const float* fb = fT + (size_t)col * (FHh*CC) + lane;
            a += c0.x*fb[0*64]  + c0.y*fb[1*64]  + c0.z*fb[2*64]  + c0.w*fb[3*64]
               + c1.x*fb[4*64]  + c1.y*fb[5*64]  + c1.z*fb[6*64]  + c1.w*fb[7*64]
               + c2.x*fb[8*64]  + c2.y*fb[9*64]  + c2.z*fb[10*64] + c2.w*fb[11*64]
               + c3.x*fb[12*64] + c3.y*fb[13*64] + c3.z*fb[14*64] + c3.w*fb[15*64];
            ptr = rec[1];
        }
        s_acc[lane*65 + cell] = a;           // c = lane
    }
    __syncthreads();

    // coalesced float4 writes: out[bz][c][xy0 .. xy0+63]
    float* dst = out + (size_t)bz * CC * XYg + xy0;
    #pragma unroll
    for (int rep = 0; rep < 4; ++rep) {
        int c = (wv << 4) + (rep << 2) + (lane >> 4);   // 0..63
        int q = lane & 15;
        float4 v = make_float4(s_acc[c*65 + 4*q + 0], s_acc[c*65 + 4*q + 1],
                               s_acc[c*65 + 4*q + 2], s_acc[c*65 + 4*q + 3]);
        ((float4*)(dst + (size_t)c * XYg))[q] = v;
    }
}

// -------- fallback (tiny ws): direct atomics into out, final layout --------
__global__ __launch_bounds__(256)
void lss_scatter_direct(const float* __restrict__ xf,
                        const float* __restrict__ rots,
                        const float* __restrict__ trans,
                        const float* __restrict__ intr,
                        const float* __restrict__ prots,
                        const float* __restrict__ ptrans,
                        float* __restrict__ acc)
{
    const int wid  = blockIdx.x * 4 + (threadIdx.x >> 6);
    const int lane = threadIdx.x & 63;
    if (wid >= NPIX) return;
    int w  = wid % FWw;
    int t1 = wid / FWw;
    int h  = t1 % FHh; t1 /= FHh;
    int n  = t1 % NN;
    int b  = t1 / NN;
    const int cam = b*NN + n;

    double K9[9], P9[9], R9[9];
    #pragma unroll
    for (int i = 0; i < 9; ++i) {
        K9[i] = (double)intr [cam*9 + i];
        P9[i] = (double)prots[cam*9 + i];
        R9[i] = (double)rots [cam*9 + i];
    }
    double Kinv[9], Pinv[9];
    inv3x3d(K9, Kinv);
    inv3x3d(P9, Pinv);
    double M[9];
    #pragma unroll
    for (int i = 0; i < 3; ++i)
        #pragma unroll
        for (int j = 0; j < 3; ++j)
            M[i*3+j] = R9[i*3+0]*Kinv[0*3+j] + R9[i*3+1]*Kinv[1*3+j] + R9[i*3+2]*Kinv[2*3+j];
    const double tx  = (double)trans [cam*3+0], ty  = (double)trans [cam*3+1], tz  = (double)trans [cam*3+2];
    const double ptx = (double)ptrans[cam*3+0], pty = (double)ptrans[cam*3+1], ptz = (double)ptrans[cam*3+2];

    const size_t pixoff = (size_t)cam * (DD+CC) * FHh * FWw + (size_t)h * FWw + w;
    float logit = (lane < DD) ? xf[pixoff + (size_t)lane * (FHh*FWw)] : -INFINITY;
    float mx = logit;
    #pragma unroll
    for (int off = 32; off; off >>= 1) mx = fmaxf(mx, __shfl_xor(mx, off));
    float ex = (lane < DD) ? expf(logit - mx) : 0.0f;
    float sm = ex;
    #pragma unroll
    for (int off = 32; off; off >>= 1) sm += __shfl_xor(sm, off);
    const float wgt = ex / sm;

    int baddr = -1;
    if (lane < DD) {
        double dz = 4.0 + (double)lane;
        double xs = (double)w * (703.0/43.0);
        double ys = (double)h * 17.0;
        double px = xs - ptx, py = ys - pty, pz = dz - ptz;
        double qx = Pinv[0]*px + Pinv[1]*py + Pinv[2]*pz;
        double qy = Pinv[3]*px + Pinv[4]*py + Pinv[5]*pz;
        double qz = Pinv[6]*px + Pinv[7]*py + Pinv[8]*pz;
        qx *= qz; qy *= qz;
        double gx = M[0]*qx + M[1]*qy + M[2]*qz + tx;
        double gy = M[3]*qx + M[4]*qy + M[5]*qz + ty;
        double gz = M[6]*qx + M[7]*qy + M[8]*qz + tz;
        double fx = floor((gx + 50.0) / 0.5);
        double fy = floor((gy + 50.0) / 0.5);
        double fz = floor((gz + 10.0) / 20.0);
        if (fx >= 0.0 && fx < (double)NXg &&
            fy >= 0.0 && fy < (double)NYg &&
            fz >= 0.0 && fz < (double)NZg) {
            int ix = (int)fx, iy = (int)fy, iz = (int)fz;
            int bz = b*NZg + iz;
            baddr = bz * (CC*XYg) + ix*NYg + iy;
        }
    }

    const float f = xf[pixoff + (size_t)(DD + lane) * (FHh*FWw)];
    for (int d = 0; d < DD; ++d) {
        int   a  = __shfl(baddr, d);
        float wd = __shfl(wgt,   d);
        if (a >= 0) atomicAdd(&acc[(size_t)a + (size_t)lane * XYg], wd * f);
    }
}

__global__ __launch_bounds__(256)
void lss_zero(float4* __restrict__ p, int n4)
{
    const int stride = gridDim.x * 256;
    for (int i = blockIdx.x * 256 + threadIdx.x; i < n4; i += stride)
        p[i] = make_float4(0.f, 0.f, 0.f, 0.f);
}

extern "C" void kernel_launch(void* const* d_in, const int* in_sizes, int n_in,
                              void* d_out, int out_size, void* d_ws, size_t ws_size,
                              hipStream_t stream) {
    const float* xf     = (const float*)d_in[0];
    const float* rots   = (const float*)d_in[1];
    const float* trans  = (const float*)d_in[2];
    const float* intr   = (const float*)d_in[3];
    const float* prots  = (const float*)d_in[4];
    const float* ptrans = (const float*)d_in[5];
    float* out = (float*)d_out;

    if (ws_size >= (size_t)WS_NEED) {
        char* wsb = (char*)d_ws;
        int*   head = (int*)(wsb + HEAD_OFF);
        int*   cnt  = (int*)(wsb + CNT_OFF);
        int*   recs = (int*)(wsb + REC_OFF);
        float* fT   = (float*)(wsb + FT_OFF);
        hipMemsetAsync(head, 0xFF, (size_t)NVOX * sizeof(int), stream);
        hipMemsetAsync(cnt, 0, sizeof(int), stream);
        lss_build<<<dim3(NCOL), dim3(256), 0, stream>>>(
            xf, rots, trans, intr, prots, ptrans, head, cnt, recs, fT);
        lss_gather<<<dim3(BB*NZg*625), dim3(256), 0, stream>>>(head, recs, fT, out);
    } else {
        lss_zero<<<dim3(2048), dim3(256), 0, stream>>>(
            (float4*)out, (BB*NZg*XYg*CC)/4);
        lss_scatter_direct<<<dim3((NPIX + 3) / 4), dim3(256), 0, stream>>>(
            xf, rots, trans, intr, prots, ptrans, out);
    }
}

// Round 10
// 54.911 us; speedup vs baseline: 1.5792x; 1.5792x over previous
//
#include <hip/hip_runtime.h>
#include <math.h>

#define BB 4
#define NN 6
#define DD 41
#define CC 64
#define FHh 16
#define FWw 44
#define NXg 200
#define NYg 200
#define NZg 1
#define NSLOT 128
#define NOVF  (FHh*DD)                 // 656 worst-case points per column
#define XYg (NXg*NYg)                  // 40000
#define NVOX (BB*NZg*NXg*NYg)          // 160000
#define NCOL (BB*NN*FWw)               // 1056 columns
#define NPIX (BB*NN*FHh*FWw)           // 16896
#define MAXOVF (NCOL*NOVF)             // 692736 worst case

// ---- ws byte offsets ----
#define BM_OFF    0u                   // bitmap: 20000 B (1 bit / voxel)
#define OVFC_OFF  20480u               // global overflow counter (int)
#define NCNT_OFF  24576u               // 1056 ints
#define VOXL_OFF  32768u               // 1056*128 ints        = 540672
#define COEF_OFF  573440u              // 1056*128*16 floats   = 8650752
#define FT_OFF    9224192u             // 1056*16*64 floats    = 4325376
#define WSV_OFF   13549568u            // 160000*64 floats     = 40960000
#define OVFR_OFF  54509568u            // MAXOVF*16 B          = 11083776
#define WS_NEED   65593344u            // ~65.6 MB

__device__ __forceinline__ void inv3x3d(const double m[9], double o[9]) {
    double a=m[0],b=m[1],c=m[2],d=m[3],e=m[4],f=m[5],g=m[6],h=m[7],i=m[8];
    double A = e*i - f*h;
    double Bv = -(d*i - f*g);
    double Cv = d*h - e*g;
    double det = a*A + b*Bv + c*Cv;
    double r = 1.0/det;
    o[0]=A*r;  o[1]=-(b*i-c*h)*r; o[2]=(b*f-c*e)*r;
    o[3]=Bv*r; o[4]=(a*i-c*g)*r;  o[5]=-(a*f-c*d)*r;
    o[6]=Cv*r; o[7]=-(a*h-b*g)*r; o[8]=(a*e-b*d)*r;
}

__global__ __launch_bounds__(256)
void lss_zero(float4* __restrict__ p, int n4)
{
    const int stride = gridDim.x * 256;
    for (int i = blockIdx.x * 256 + threadIdx.x; i < n4; i += stride)
        p[i] = make_float4(0.f, 0.f, 0.f, 0.f);
}

// ---------------- K1: build lists, zero own ws rows, set bitmap -------------
__global__ __launch_bounds__(256)
void lss_build(const float* __restrict__ xf,
               const float* __restrict__ rots,
               const float* __restrict__ trans,
               const float* __restrict__ intr,
               const float* __restrict__ prots,
               const float* __restrict__ ptrans,
               char* __restrict__ wsb)
{
    unsigned int* bm   = (unsigned int*)(wsb + BM_OFF);
    int*   ovfc = (int*)  (wsb + OVFC_OFF);
    int*   ncnt = (int*)  (wsb + NCNT_OFF);
    int*   voxl = (int*)  (wsb + VOXL_OFF);
    float* coefG= (float*)(wsb + COEF_OFF);
    float* fT   = (float*)(wsb + FT_OFF);
    float* wsv  = (float*)(wsb + WSV_OFF);
    int*   ovfr = (int*)  (wsb + OVFR_OFF);

    __shared__ float s_lg[FHh * FWw];
    __shared__ float s_feat[FHh * CC];
    __shared__ float s_coef[NSLOT * 17];
    __shared__ int   s_keys[NSLOT];
    __shared__ short s_list[NSLOT];
    __shared__ int   s_nslot;
    __shared__ int2  s_ovf[NOVF];
    __shared__ float s_ovfw[NOVF];
    __shared__ int   s_ovfcnt;

    const int tid  = threadIdx.x;
    const int lane = tid & 63;
    const int wv   = tid >> 6;          // 0..3

    // XCD swizzle: 1056 = 8*132
    const int obid = blockIdx.x;
    const int bid  = (obid & 7) * (NCOL / 8) + (obid >> 3);
    const int w   = bid % FWw;
    const int rem = bid / FWw;
    const int n   = rem % NN;
    const int b   = rem / NN;
    const int cam = b*NN + n;
    const float* colbase = xf + (size_t)cam * (DD+CC) * FHh * FWw + w;

    if (tid < NSLOT) s_keys[tid] = -1;
    for (int i = tid; i < NSLOT*17; i += 256) s_coef[i] = 0.0f;
    if (tid == 0) { s_nslot = 0; s_ovfcnt = 0; }

    // stage the whole column (1680 scalars)
    for (int t = tid; t < (DD+CC)*FHh; t += 256) {
        int h  = t / (DD+CC);
        int ch = t - h*(DD+CC);
        float v = colbase[(size_t)ch * (FHh*FWw) + h * FWw];
        if (ch < DD) s_lg[h*FWw + ch] = v;
        else         s_feat[(h << 6) + (ch - DD)] = v;
    }

    // per-camera transform (f64, redundant per thread)
    double K9[9], P9[9], R9[9];
    #pragma unroll
    for (int i = 0; i < 9; ++i) {
        K9[i] = (double)intr [cam*9 + i];
        P9[i] = (double)prots[cam*9 + i];
        R9[i] = (double)rots [cam*9 + i];
    }
    double Kinv[9], Pinv[9];
    inv3x3d(K9, Kinv);
    inv3x3d(P9, Pinv);
    double M[9];
    #pragma unroll
    for (int i = 0; i < 3; ++i)
        #pragma unroll
        for (int j = 0; j < 3; ++j)
            M[i*3+j] = R9[i*3+0]*Kinv[0*3+j] + R9[i*3+1]*Kinv[1*3+j] + R9[i*3+2]*Kinv[2*3+j];
    const double tx  = (double)trans [cam*3+0], ty  = (double)trans [cam*3+1], tz  = (double)trans [cam*3+2];
    const double ptx = (double)ptrans[cam*3+0], pty = (double)ptrans[cam*3+1], ptz = (double)ptrans[cam*3+2];

    __syncthreads();

    // softmax + geometry + hash insert; wave wv handles h = 4wv..4wv+3
    int      last_vox  = -1;
    unsigned last_slot = 0;
    for (int r = 0; r < 4; ++r) {
        const int h = (wv << 2) + r;
        float logit = (lane < DD) ? s_lg[h*FWw + lane] : -INFINITY;
        float mx = logit;
        #pragma unroll
        for (int off = 32; off; off >>= 1) mx = fmaxf(mx, __shfl_xor(mx, off));
        float ex = (lane < DD) ? expf(logit - mx) : 0.0f;
        float sm = ex;
        #pragma unroll
        for (int off = 32; off; off >>= 1) sm += __shfl_xor(sm, off);
        const float wgt = ex / sm;

        int vox = -1;
        if (lane < DD) {
            double dz = 4.0 + (double)lane;
            double xs = (double)w * (703.0/43.0);
            double ys = (double)h * 17.0;
            double px = xs - ptx, py = ys - pty, pz = dz - ptz;
            double qx = Pinv[0]*px + Pinv[1]*py + Pinv[2]*pz;
            double qy = Pinv[3]*px + Pinv[4]*py + Pinv[5]*pz;
            double qz = Pinv[6]*px + Pinv[7]*py + Pinv[8]*pz;
            qx *= qz; qy *= qz;
            double gx = M[0]*qx + M[1]*qy + M[2]*qz + tx;
            double gy = M[3]*qx + M[4]*qy + M[5]*qz + ty;
            double gz = M[6]*qx + M[7]*qy + M[8]*qz + tz;
            double fx = floor((gx + 50.0) / 0.5);
            double fy = floor((gy + 50.0) / 0.5);
            double fz = floor((gz + 10.0) / 20.0);
            if (fx >= 0.0 && fx < (double)NXg &&
                fy >= 0.0 && fy < (double)NYg &&
                fz >= 0.0 && fz < (double)NZg) {
                int ix = (int)fx, iy = (int)fy, iz = (int)fz;
                vox = ((b*NZg + iz)*NXg + ix)*NYg + iy;   // < NVOX
            }
        }

        if (vox >= 0) {
            if (vox == last_vox) {
                atomicAdd(&s_coef[last_slot*17 + h], wgt);
            } else {
                unsigned slot = (((unsigned)vox * 2654435761u) >> 18) & (NSLOT-1);
                bool done = false;
                for (int probe = 0; probe < NSLOT; ++probe) {
                    int prev = atomicCAS(&s_keys[slot], -1, vox);
                    if (prev == -1) {
                        int k = atomicAdd(&s_nslot, 1);
                        s_list[k] = (short)slot;
                    }
                    if (prev == -1 || prev == vox) {
                        atomicAdd(&s_coef[slot*17 + h], wgt);
                        last_vox = vox; last_slot = slot;
                        done = true;
                        break;
                    }
                    slot = (slot + 1) & (NSLOT-1);
                }
                if (!done) {
                    int k = atomicAdd(&s_ovfcnt, 1);
                    s_ovf[k]  = make_int2(vox, h);
                    s_ovfw[k] = wgt;
                    last_vox = -1;
                }
            }
        }
    }

    __syncthreads();

    const int nocc = s_nslot;
    const int novf = s_ovfcnt;

    // publish features fT[bid][h][c] (coalesced)
    {
        float* ft = fT + (size_t)bid * (FHh*CC);
        for (int i = tid; i < FHh*CC; i += 256) ft[i] = s_feat[i];
    }
    // publish count + voxel list + coefficients (coalesced)
    if (tid == 0) ncnt[bid] = nocc;
    for (int e = tid; e < nocc; e += 256)
        voxl[bid*NSLOT + e] = s_keys[s_list[e]];
    for (int i = tid; i < nocc*16; i += 256) {
        int e = i >> 4, hh = i & 15;
        coefG[((size_t)bid*NSLOT + e)*16 + hh] = s_coef[s_list[e]*17 + hh];
    }
    // zero own ws rows + set bitmap (plain stores; K1->K2 boundary orders them)
    for (int e = wv; e < nocc; e += 4) {
        int vox = s_keys[s_list[e]];
        wsv[(size_t)vox * CC + lane] = 0.0f;
        if (lane == 0) atomicOr(&bm[vox >> 5], 1u << (vox & 31));
    }
    // overflow records (rare)
    for (int e = wv; e < novf; e += 4) {
        int vox = s_ovf[e].x, h = s_ovf[e].y;
        int ridx = 0;
        if (lane == 0) ridx = atomicAdd(ovfc, 1);
        ridx = __shfl(ridx, 0);
        if (ridx < MAXOVF) {
            if (lane == 0) {
                int* rec = ovfr + (size_t)ridx * 4;
                rec[0] = vox; rec[1] = bid; rec[2] = h;
                ((float*)rec)[3] = s_ovfw[e];
            }
            wsv[(size_t)vox * CC + lane] = 0.0f;
            if (lane == 0) atomicOr(&bm[vox >> 5], 1u << (vox & 31));
        }
    }
}

// ---------------- K2: emit atomics into zeroed ws rows ----------------------
__global__ __launch_bounds__(256)
void lss_emit(char* __restrict__ wsb)
{
    const int*   ovfc = (const int*)  (wsb + OVFC_OFF);
    const int*   ncnt = (const int*)  (wsb + NCNT_OFF);
    const int*   voxl = (const int*)  (wsb + VOXL_OFF);
    const float* coefG= (const float*)(wsb + COEF_OFF);
    const float* fT   = (const float*)(wsb + FT_OFF);
    float*       wsv  = (float*)      (wsb + WSV_OFF);
    const int*   ovfr = (const int*)  (wsb + OVFR_OFF);

    __shared__ float s_feat[FHh * CC];
    __shared__ float s_cf[NSLOT * 16];
    __shared__ int   s_vox[NSLOT];

    const int tid  = threadIdx.x;
    const int lane = tid & 63;
    const int wv   = tid >> 6;

    const int obid = blockIdx.x;
    const int bid  = (obid & 7) * (NCOL / 8) + (obid >> 3);

    const int nocc = ncnt[bid];
    // stage features + coefficients + voxel list (all coalesced)
    {
        const float* ft = fT + (size_t)bid * (FHh*CC);
        for (int i = tid; i < FHh*CC; i += 256) s_feat[i] = ft[i];
        for (int i = tid; i < nocc*16; i += 256)
            s_cf[i] = coefG[(size_t)bid*NSLOT*16 + i];
        for (int e = tid; e < nocc; e += 256)
            s_vox[e] = voxl[bid*NSLOT + e];
    }
    __syncthreads();

    for (int e = wv; e < nocc; e += 4) {
        int vox = s_vox[e];
        float acc = 0.0f;
        #pragma unroll
        for (int h = 0; h < FHh; ++h)
            acc += s_cf[e*16 + h] * s_feat[(h << 6) + lane];
        atomicAdd(&wsv[(size_t)vox * CC + lane], acc);
    }

    // overflow (rare): block strides the global record list with wave 0
    const int nov = min(*ovfc, MAXOVF);
    for (int ridx = obid; ridx < nov; ridx += NCOL) {
        if (wv == 0) {
            const int* rec = ovfr + (size_t)ridx * 4;
            int vox = rec[0], col = rec[1], h = rec[2];
            float wgt = ((const float*)rec)[3];
            float f = fT[(size_t)col * (FHh*CC) + (h << 6) + lane];
            atomicAdd(&wsv[(size_t)vox * CC + lane], wgt * f);
        }
    }
}

// ------- K3: ws [vox][64c] -> out [bz][c][xy], bitmap-gated tile reads ------
__global__ __launch_bounds__(256)
void lss_transpose_b(const char* __restrict__ wsb, float* __restrict__ out)
{
    const unsigned int* bm = (const unsigned int*)(wsb + BM_OFF);
    const float* wsv = (const float*)(wsb + WSV_OFF);

    __shared__ float tile[CC][65];
    const int blk  = blockIdx.x;            // 4*625
    const int bz   = blk / 625;
    const int xy0  = (blk % 625) * 64;
    const int t    = threadIdx.x;
    const int lane = t & 63;
    const int wv   = t >> 6;

    const int vb = bz * XYg + xy0;          // 32-aligned
    const unsigned int touched = bm[vb >> 5] | bm[(vb >> 5) + 1];

    float* dst = out + (size_t)bz * CC * XYg + xy0;
    if (touched == 0u) {
        const float4 z = make_float4(0.f, 0.f, 0.f, 0.f);
        #pragma unroll
        for (int rep = 0; rep < 4; ++rep) {
            int c = (wv << 4) + (rep << 2) + (lane >> 4);
            int q = lane & 15;
            ((float4*)(dst + (size_t)c * XYg))[q] = z;
        }
        return;
    }

    const float4* src = (const float4*)(wsv + (size_t)vb * CC);
    #pragma unroll
    for (int rep = 0; rep < 4; ++rep) {
        int idx = (wv << 8) + (rep << 6) + lane;
        int xyl = idx >> 4;
        int c4  = idx & 15;
        float4 v = src[idx];
        tile[(c4<<2)+0][xyl] = v.x;
        tile[(c4<<2)+1][xyl] = v.y;
        tile[(c4<<2)+2][xyl] = v.z;
        tile[(c4<<2)+3][xyl] = v.w;
    }
    __syncthreads();
    #pragma unroll
    for (int rep = 0; rep < 4; ++rep) {
        int c = (wv << 4) + (rep << 2) + (lane >> 4);
        int q = lane & 15;
        float4 v = make_float4(tile[c][(q<<2)+0], tile[c][(q<<2)+1],
                               tile[c][(q<<2)+2], tile[c][(q<<2)+3]);
        ((float4*)(dst + (size_t)c * XYg))[q] = v;
    }
}

// ---------------- fallback (tiny ws): zero out + direct atomics -------------
__global__ __launch_bounds__(256)
void lss_scatter_direct(const float* __restrict__ xf,
                        const float* __restrict__ rots,
                        const float* __restrict__ trans,
                        const float* __restrict__ intr,
                        const float* __restrict__ prots,
                        const float* __restrict__ ptrans,
                        float* __restrict__ acc)
{
    const int wid  = blockIdx.x * 4 + (threadIdx.x >> 6);
    const int lane = threadIdx.x & 63;
    if (wid >= NPIX) return;
    int w  = wid % FWw;
    int t1 = wid / FWw;
    int h  = t1 % FHh; t1 /= FHh;
    int n  = t1 % NN;
    int b  = t1 / NN;
    const int cam = b*NN + n;

    double K9[9], P9[9], R9[9];
    #pragma unroll
    for (int i = 0; i < 9; ++i) {
        K9[i] = (double)intr [cam*9 + i];
        P9[i] = (double)prots[cam*9 + i];
        R9[i] = (double)rots [cam*9 + i];
    }
    double Kinv[9], Pinv[9];
    inv3x3d(K9, Kinv);
    inv3x3d(P9, Pinv);
    double M[9];
    #pragma unroll
    for (int i = 0; i < 3; ++i)
        #pragma unroll
        for (int j = 0; j < 3; ++j)
            M[i*3+j] = R9[i*3+0]*Kinv[0*3+j] + R9[i*3+1]*Kinv[1*3+j] + R9[i*3+2]*Kinv[2*3+j];
    const double tx  = (double)trans [cam*3+0], ty  = (double)trans [cam*3+1], tz  = (double)trans [cam*3+2];
    const double ptx = (double)ptrans[cam*3+0], pty = (double)ptrans[cam*3+1], ptz = (double)ptrans[cam*3+2];

    const size_t pixoff = (size_t)cam * (DD+CC) * FHh * FWw + (size_t)h * FWw + w;
    float logit = (lane < DD) ? xf[pixoff + (size_t)lane * (FHh*FWw)] : -INFINITY;
    float mx = logit;
    #pragma unroll
    for (int off = 32; off; off >>= 1) mx = fmaxf(mx, __shfl_xor(mx, off));
    float ex = (lane < DD) ? expf(logit - mx) : 0.0f;
    float sm = ex;
    #pragma unroll
    for (int off = 32; off; off >>= 1) sm += __shfl_xor(sm, off);
    const float wgt = ex / sm;

    int baddr = -1;
    if (lane < DD) {
        double dz = 4.0 + (double)lane;
        double xs = (double)w * (703.0/43.0);
        double ys = (double)h * 17.0;
        double px = xs - ptx, py = ys - pty, pz = dz - ptz;
        double qx = Pinv[0]*px + Pinv[1]*py + Pinv[2]*pz;
        double qy = Pinv[3]*px + Pinv[4]*py + Pinv[5]*pz;
        double qz = Pinv[6]*px + Pinv[7]*py + Pinv[8]*pz;
        qx *= qz; qy *= qz;
        double gx = M[0]*qx + M[1]*qy + M[2]*qz + tx;
        double gy = M[3]*qx + M[4]*qy + M[5]*qz + ty;
        double gz = M[6]*qx + M[7]*qy + M[8]*qz + tz;
        double fx = floor((gx + 50.0) / 0.5);
        double fy = floor((gy + 50.0) / 0.5);
        double fz = floor((gz + 10.0) / 20.0);
        if (fx >= 0.0 && fx < (double)NXg &&
            fy >= 0.0 && fy < (double)NYg &&
            fz >= 0.0 && fz < (double)NZg) {
            int ix = (int)fx, iy = (int)fy, iz = (int)fz;
            int bz = b*NZg + iz;
            baddr = bz * (CC*XYg) + ix*NYg + iy;
        }
    }

    const float f = xf[pixoff + (size_t)(DD + lane) * (FHh*FWw)];
    for (int d = 0; d < DD; ++d) {
        int   a  = __shfl(baddr, d);
        float wd = __shfl(wgt,   d);
        if (a >= 0) atomicAdd(&acc[(size_t)a + (size_t)lane * XYg], wd * f);
    }
}

extern "C" void kernel_launch(void* const* d_in, const int* in_sizes, int n_in,
                              void* d_out, int out_size, void* d_ws, size_t ws_size,
                              hipStream_t stream) {
    const float* xf     = (const float*)d_in[0];
    const float* rots   = (const float*)d_in[1];
    const float* trans  = (const float*)d_in[2];
    const float* intr   = (const float*)d_in[3];
    const float* prots  = (const float*)d_in[4];
    const float* ptrans = (const float*)d_in[5];
    float* out = (float*)d_out;

    if (ws_size >= (size_t)WS_NEED) {
        char* wsb = (char*)d_ws;
        // zero control region only (bitmap + ovf counter): 32 KB
        lss_zero<<<dim3(8), dim3(256), 0, stream>>>((float4*)wsb, 32768/16);
        lss_build<<<dim3(NCOL), dim3(256), 0, stream>>>(
            xf, rots, trans, intr, prots, ptrans, wsb);
        lss_emit<<<dim3(NCOL), dim3(256), 0, stream>>>(wsb);
        lss_transpose_b<<<dim3(BB*NZg*625), dim3(256), 0, stream>>>(wsb, out);
    } else {
        lss_zero<<<dim3(2048), dim3(256), 0, stream>>>(
            (float4*)out, (BB*NZg*XYg*CC)/4);
        lss_scatter_direct<<<dim3((NPIX + 3) / 4), dim3(256), 0, stream>>>(
            xf, rots, trans, intr, prots, ptrans, out);
    }
}